// Round 7
// baseline (277.416 us; speedup 1.0000x reference)
//
#include <hip/hip_runtime.h>
#include <hip/hip_bf16.h>
#include <math.h>

#define B_ 2
#define T_ 2048
#define D_ 2048
#define H_ 16
#define KV_ 4
#define HD_ 128
#define REP_ 4
#define QKVSTR 3072

typedef __attribute__((ext_vector_type(8))) short s16x8;
typedef __attribute__((ext_vector_type(4))) short s16x4;
typedef __attribute__((ext_vector_type(4))) float f32x4;
typedef __attribute__((ext_vector_type(16))) float f32x16;
typedef __hip_bfloat16 bf16;

__device__ __forceinline__ short f2bf(float x) {
    bf16 h = __float2bfloat16(x);
    return *reinterpret_cast<short*>(&h);
}

__device__ __forceinline__ void gl2lds16(const void* g, void* l) {
    __builtin_amdgcn_global_load_lds(
        (const __attribute__((address_space(1))) char*)g,
        (__attribute__((address_space(3))) char*)l, 16, 0, 0);
}

// ---------------- fused prep: cast x -> bf16  +  all 4 weight transposes ----
// (see r5 notes: conflict-free u32 transpose, 33-word stride)
__global__ __launch_bounds__(256) void prep(const float* __restrict__ x,
                                            const float* __restrict__ Wq,
                                            const float* __restrict__ Wk,
                                            const float* __restrict__ Wv,
                                            const float* __restrict__ Wo,
                                            bf16* __restrict__ xb,
                                            bf16* __restrict__ Wqkvt,
                                            bf16* __restrict__ Wot,
                                            float qscale) {
    const int bid = blockIdx.x;
    const int t = threadIdx.x;
    if (bid < 4096) {
        int i = (bid * 256 + t) * 8;
        float4 a = *(const float4*)(x + i);
        float4 b = *(const float4*)(x + i + 4);
        short o[8] = {f2bf(a.x), f2bf(a.y), f2bf(a.z), f2bf(a.w),
                      f2bf(b.x), f2bf(b.y), f2bf(b.z), f2bf(b.w)};
        *(s16x8*)(xb + i) = *(const s16x8*)o;
        return;
    }
    __shared__ unsigned tileT[64 * 33];   // 8448 B, u32 = one k-pair
    const float* W; bf16* dst; int N; float scale; int seg;
    if (bid < 5120)      { seg = bid - 4096; W = Wq; dst = Wqkvt;                      N = 2048; scale = qscale; }
    else if (bid < 5376) { seg = bid - 5120; W = Wk; dst = Wqkvt + (size_t)2048 * D_;  N = 512;  scale = 1.f; }
    else if (bid < 5632) { seg = bid - 5376; W = Wv; dst = Wqkvt + (size_t)2560 * D_;  N = 512;  scale = 1.f; }
    else                 { seg = bid - 5632; W = Wo; dst = Wot;                        N = 2048; scale = 1.f; }
    const int k0 = (seg & 31) * 64, n0 = (seg >> 5) * 64;

    const int r2 = t >> 3;            // k-pair 0..31
    const int c0 = (t & 7) * 8;       // col offset 0..56
    const float* srcA = W + (size_t)(k0 + 2 * r2) * N + n0 + c0;
    const float* srcB = srcA + N;
    float4 a0 = *(const float4*)(srcA);
    float4 a1 = *(const float4*)(srcA + 4);
    float4 b0 = *(const float4*)(srcB);
    float4 b1 = *(const float4*)(srcB + 4);
    float ra[8] = {a0.x, a0.y, a0.z, a0.w, a1.x, a1.y, a1.z, a1.w};
    float rb[8] = {b0.x, b0.y, b0.z, b0.w, b1.x, b1.y, b1.z, b1.w};
    #pragma unroll
    for (int j = 0; j < 8; ++j) {
        unsigned p;
        asm("v_cvt_pk_bf16_f32 %0, %1, %2"
            : "=v"(p) : "v"(ra[j] * scale), "v"(rb[j] * scale));
        tileT[(c0 + j) * 33 + r2] = p;
    }
    __syncthreads();
    const int n = t >> 2, q = t & 3;
    union { unsigned u[8]; s16x8 v[2]; } ou;
    #pragma unroll
    for (int j = 0; j < 8; ++j) ou.u[j] = tileT[n * 33 + q * 8 + j];
    bf16* d = dst + (size_t)(n0 + n) * D_ + k0 + q * 16;
    *(s16x8*)(d)     = ou.v[0];
    *(s16x8*)(d + 8) = ou.v[1];
}

// ---- bf16 NT GEMM, 8-wave BMxBN tile, counted-vmcnt pipeline (T4) ---------
// (unchanged from r5 — see comments there)
template<int MI, int NJ, typename OUTT, int ROUND, int WVT>
__global__ __launch_bounds__(512, 2) void gemm8(const bf16* __restrict__ A,
                                                const bf16* __restrict__ Bt,
                                                OUTT* __restrict__ C,
                                                bf16* __restrict__ Vtg,
                                                int M, int N, int K) {
    constexpr int ASZ = MI * 2048;          // shorts per A buffer (MI*32 x 64)
    constexpr int BSZ = NJ * 4096;          // shorts per B buffer (NJ*64 x 64)
    __shared__ short smem[2 * (ASZ + BSZ)];
    const int tid = threadIdx.x;
    const int lane = tid & 63;
    const int wave = tid >> 6;
    const int quad = lane >> 4;
    const int l16 = lane & 15;
    const int wr = wave >> 2, wc = wave & 3;      // 2 x 4 wave grid
    const int row0 = blockIdx.y * (MI * 32);
    const int col0 = blockIdx.x * (NJ * 64);
    const int NT = K >> 6;

    f32x4 acc[MI][NJ] = {};

    const bf16* Ap = A + (size_t)row0 * K;
    const bf16* Bp = Bt + (size_t)col0 * K;

    auto stage = [&](int t) {
        const int bo = (t & 1) * (ASZ + BSZ);
        const int k0 = t * 64;
        #pragma unroll
        for (int i = 0; i < MI / 2; ++i) {
            int g = i * 512 + tid;
            int row = g >> 3;
            int cs = (g & 7) ^ (row & 7);
            gl2lds16(Ap + (size_t)row * K + k0 + cs * 8, &smem[bo + g * 8]);
        }
        #pragma unroll
        for (int i = 0; i < NJ; ++i) {
            int g = i * 512 + tid;
            int row = g >> 3;
            int cs = (g & 7) ^ (row & 7);
            gl2lds16(Bp + (size_t)row * K + k0 + cs * 8, &smem[bo + ASZ + g * 8]);
        }
    };

    constexpr int VM = MI / 2 + NJ;         // loads per stage = in-flight count
    static_assert(VM == 6 || VM == 7, "add a vmcnt literal for this shape");

    stage(0);
    for (int t = 0; t < NT; ++t) {
        if (t + 1 < NT) {
            stage(t + 1);
            if constexpr (VM == 7) asm volatile("s_waitcnt vmcnt(7)" ::: "memory");
            else                   asm volatile("s_waitcnt vmcnt(6)" ::: "memory");
        } else {
            asm volatile("s_waitcnt vmcnt(0)" ::: "memory");
        }
        __builtin_amdgcn_s_barrier();
        asm volatile("" ::: "memory");

        const int bo = (t & 1) * (ASZ + BSZ);
        #pragma unroll
        for (int kk = 0; kk < 2; ++kk) {
            s16x8 af[MI], bfr[NJ];
            #pragma unroll
            for (int i = 0; i < MI; ++i) {
                int row = wr * (MI * 16) + i * 16 + l16;
                int c = (kk * 4 + quad) ^ (row & 7);
                af[i] = *(const s16x8*)&smem[bo + row * 64 + c * 8];
            }
            #pragma unroll
            for (int j = 0; j < NJ; ++j) {
                int row = wc * (NJ * 16) + j * 16 + l16;
                int c = (kk * 4 + quad) ^ (row & 7);
                bfr[j] = *(const s16x8*)&smem[bo + ASZ + row * 64 + c * 8];
            }
            __builtin_amdgcn_s_setprio(1);
            #pragma unroll
            for (int i = 0; i < MI; ++i)
                #pragma unroll
                for (int j = 0; j < NJ; ++j)
                    acc[i][j] = __builtin_amdgcn_mfma_f32_16x16x32_bf16(
                        af[i], bfr[j], acc[i][j], 0, 0, 0);
            __builtin_amdgcn_s_setprio(0);
        }
        asm volatile("s_waitcnt lgkmcnt(0)" ::: "memory");
        __builtin_amdgcn_s_barrier();
        asm volatile("" ::: "memory");
    }

    #pragma unroll
    for (int i = 0; i < MI; ++i) {
        #pragma unroll
        for (int j = 0; j < NJ; ++j) {
            const int col = col0 + wc * (NJ * 16) + j * 16 + l16;
            const int rowb = row0 + wr * (MI * 16) + i * 16 + quad * 4;
            #pragma unroll
            for (int r = 0; r < 4; ++r) {
                float v = acc[i][j][r];
                if (ROUND) v = rintf(v * 1e4f) * 1e-4f;
                if constexpr (sizeof(OUTT) == 2)
                    C[(size_t)(rowb + r) * N + col] = __float2bfloat16(v);
                else
                    C[(size_t)(rowb + r) * N + col] = v;
            }
            if constexpr (WVT) {
                if (col >= 2560) {
                    const int dcol = (col - 2560) & 127;
                    const int g = (col - 2560) >> 7;
                    const int b = rowb >> 11;
                    const int t = rowb & 2047;
                    short pk[4] = {f2bf(acc[i][j][0]), f2bf(acc[i][j][1]),
                                   f2bf(acc[i][j][2]), f2bf(acc[i][j][3])};
                    *(s16x4*)&Vtg[(size_t)((b * KV_ + g) * HD_ + dcol) * T_ + t] =
                        *(const s16x4*)pk;
                }
            }
        }
    }
}

// ---------------- MFMA flash attention v11: software-pipelined softmax -----
// flash9 (75.8 us) was stall-bound (2.7x over max pipe floor): per tile the
// wave runs QK-reads -> QK-MFMA -> softmax-VALU -> PV serially, with only
// 2 waves/SIMD to cover it. v11 overlaps tile t's QK^T (MFMA) with tile
// t-1's softmax+PV (VALU) inside the wave (T15 mechanism). V must survive
// one extra phase -> V TRIPLE-buffer + K SINGLE-buffer = 16+48 KB = 64 KB
// (same LDS as flash9 -> 2 blocks/CU preserved). Per-tile schedule:
//   bar A (__syncthreads: drains K(t),V(t); fences V[vnext] old readers)
//   issue V(t+1) -> Vbuf[(t+1)%3]
//   QK(t) from Kbuf -> sacc_cur
//   lgkmcnt(0); s_barrier (raw: K(t+1),V(t+1) stay IN FLIGHT across it, T4)
//   issue K(t+1) -> Kbuf   (all QK(t) reads fenced by bar B)
//   SM+PV(t-1) from sacc_prev + Vbuf[(t-1)%3]  (overlaps K(t+1) latency and
//                                               QK(t)'s MFMA pipe drain)
// sacc ping-pong statically unrolled, 2 tiles/loop-iter; tile count
// 2qt+2 is always even -> no tail (rule #20: no runtime-indexed arrays).
// Fully-masked mt-halves are skipped in SM/PV (flash9 computed exp(-inf)).
// FP op sequence per output identical to flash9 -> bit-identical results.
__global__ __launch_bounds__(256, 2) void flash11(const bf16* __restrict__ Q,
                                                  const bf16* __restrict__ K,
                                                  const bf16* __restrict__ Vtg,
                                                  bf16* __restrict__ O) {
    __shared__ short smem[32768];   // K: [0,8192) | V: 3 x 8192 @ 8192

    const int h = blockIdx.x;
    const int b = blockIdx.y & 1;
    const int qt = 15 - (blockIdx.y >> 1);   // heavy blocks first (LPT)
    const int g = h >> 2;
    const int tid = threadIdx.x;
    const int lane = tid & 63;
    const int wave = tid >> 6;
    const int l32 = lane & 31;
    const int hi = lane >> 5;
    const int qw0 = qt * 128 + wave * 32;
    const int qg = qw0 + l32;

    s16x8 qf[8];
    {
        const bf16* qp = Q + (size_t)(b * T_ + qg) * QKVSTR + h * HD_ + hi * 8;
        #pragma unroll
        for (int kt = 0; kt < 8; ++kt) qf[kt] = *(const s16x8*)(qp + kt * 16);
    }

    const bf16* Kp = K + (size_t)(b * T_) * QKVSTR + g * HD_;
    const bf16* Vp = Vtg + (size_t)((b * KV_ + g) * HD_) * T_;

    float l_part = 0.f;
    f32x16 oacc[4] = {};
    f32x16 sA[2], sB[2];

    const int jmax = 2 * qt + 1;

    auto stageK = [&](int t) {
        const int s0n = t * 64;
        #pragma unroll
        for (int i = 0; i < 4; ++i) {
            int g2 = i * 256 + tid;
            int s = g2 >> 4;
            int cs = (g2 & 15) ^ (s & 15);
            gl2lds16(Kp + (size_t)(s0n + s) * QKVSTR + cs * 8, &smem[g2 * 8]);
        }
    };
    auto stageV = [&](int t, int slot) {
        const int s0n = t * 64;
        #pragma unroll
        for (int i = 0; i < 4; ++i) {
            int g2 = i * 256 + tid;
            int d = g2 >> 3;
            int cs = (g2 & 7) ^ (d & 7);
            gl2lds16(Vp + (size_t)d * T_ + s0n + cs * 8,
                     &smem[8192 + slot * 8192 + g2 * 8]);
        }
    };

    // SM + PV for tile (s0p = t*64 of that tile), scores in prv, V in vslot
    auto smpv = [&](int s0p, f32x16* prv, int vslot) {
        #pragma unroll
        for (int mt = 0; mt < 2; ++mt) {
            if (s0p + mt * 32 >= qw0 + 32) continue;   // half fully masked
            const bool diagm = (s0p + mt * 32 + 31 > qw0);
            #pragma unroll
            for (int r = 0; r < 16; ++r) {
                float sv = prv[mt][r];
                if (diagm) {
                    int sg = s0p + mt * 32 + (r & 3) + 8 * (r >> 2) + 4 * hi;
                    if (sg > qg) sv = -INFINITY;
                }
                float e = exp2f(sv);
                prv[mt][r] = e;
                l_part += e;
            }
            #pragma unroll
            for (int kts = 0; kts < 2; ++kts) {
                const int o = kts * 8;
                unsigned w01, w23, w45, w67;
                asm("v_cvt_pk_bf16_f32 %0, %1, %2"
                    : "=v"(w01) : "v"(prv[mt][o + 0]), "v"(prv[mt][o + 1]));
                asm("v_cvt_pk_bf16_f32 %0, %1, %2"
                    : "=v"(w23) : "v"(prv[mt][o + 2]), "v"(prv[mt][o + 3]));
                asm("v_cvt_pk_bf16_f32 %0, %1, %2"
                    : "=v"(w45) : "v"(prv[mt][o + 4]), "v"(prv[mt][o + 5]));
                asm("v_cvt_pk_bf16_f32 %0, %1, %2"
                    : "=v"(w67) : "v"(prv[mt][o + 6]), "v"(prv[mt][o + 7]));
                asm("v_permlane32_swap_b32 %0, %1" : "+v"(w01), "+v"(w45));
                asm("v_permlane32_swap_b32 %0, %1" : "+v"(w23), "+v"(w67));
                union { unsigned u[4]; s16x8 v; } pu;
                pu.u[0] = w01; pu.u[1] = w23; pu.u[2] = w45; pu.u[3] = w67;
                const s16x8 pa = pu.v;
                #pragma unroll
                for (int nt = 0; nt < 4; ++nt) {
                    int d = nt * 32 + l32;
                    int c = ((mt * 2 + kts) * 2 + hi) ^ (d & 7);
                    const s16x8 vf =
                        *(const s16x8*)&smem[8192 + vslot * 8192 + d * 64 + c * 8];
                    oacc[nt] = __builtin_amdgcn_mfma_f32_32x32x16_bf16(
                        pa, vf, oacc[nt], 0, 0, 0);
                }
            }
        }
    };

    // one pipelined tile: QK(t) -> cur; then SM+PV(t-1) from prv
    auto tile = [&](int t, f32x16* cur, f32x16* prv, int vprev, int vnext) {
        __syncthreads();                       // bar A: drains K(t), V(t)
        if (t < jmax) stageV(t + 1, vnext);
        const int s0 = t * 64;
        if (s0 < qw0 + 32) {
            #pragma unroll
            for (int r = 0; r < 16; ++r) { cur[0][r] = 0.f; cur[1][r] = 0.f; }
            #pragma unroll
            for (int kt = 0; kt < 8; ++kt) {
                #pragma unroll
                for (int mt = 0; mt < 2; ++mt) {
                    int s = mt * 32 + l32;
                    int c = (kt * 2 + hi) ^ (s & 15);
                    const s16x8 kf = *(const s16x8*)&smem[s * 128 + c * 8];
                    cur[mt] = __builtin_amdgcn_mfma_f32_32x32x16_bf16(
                        kf, qf[kt], cur[mt], 0, 0, 0);
                }
            }
        }
        asm volatile("s_waitcnt lgkmcnt(0)" ::: "memory");
        __builtin_amdgcn_s_barrier();          // bar B (raw: no vmcnt drain)
        asm volatile("" ::: "memory");
        if (t < jmax) stageK(t + 1);
        if (t > 0) smpv(s0 - 64, prv, vprev);
    };

    // prologue
    stageK(0);
    stageV(0, 0);

    // main loop: tiles in pairs (count = 2qt+2, always even)
    int v0 = 0;                                // slot of tile t0 = (2p)%3
    for (int p = 0; p <= qt; ++p) {
        const int t0 = 2 * p;
        const int v1 = (v0 + 1 == 3) ? 0 : v0 + 1;   // slot of t0+1
        const int v2 = (v1 + 1 == 3) ? 0 : v1 + 1;   // slot of t0+2 == (t0-1)%3
        tile(t0,     sA, sB, v2, v1);
        tile(t0 + 1, sB, sA, v0, v2);
        v0 = v2;
    }
    // epilogue: SM+PV for tile jmax (scores in sB, slot = jmax%3)
    {
        int vlast = v0 + 2; if (vlast >= 3) vlast -= 3;
        smpv(jmax * 64, sB, vlast);
    }

    // full row sum: the other 32 s of each tile live in the lane^32 partner
    l_part += __shfl_xor(l_part, 32);
    const float invl = 1.f / l_part;     // valid for q = qw0 + l32

    // epilogue: oacc rows are q=(r&3)+8*(r>>2)+4*hi, cols d=nt*32+l32
    bf16* op = O + (size_t)(b * T_ + qw0) * (H_ * HD_) + h * HD_;
    #pragma unroll
    for (int r = 0; r < 16; ++r) {
        const int qrow = (r & 3) + 8 * (r >> 2) + 4 * hi;
        const float il = __shfl(invl, qrow);
        #pragma unroll
        for (int nt = 0; nt < 4; ++nt)
            op[(size_t)qrow * (H_ * HD_) + nt * 32 + l32] =
                __float2bfloat16(oacc[nt][r] * il);
    }
}

extern "C" void kernel_launch(void* const* d_in, const int* in_sizes, int n_in,
                              void* d_out, int out_size, void* d_ws, size_t ws_size,
                              hipStream_t stream) {
    const float* x  = (const float*)d_in[0];
    const float* Wq = (const float*)d_in[1];
    const float* Wk = (const float*)d_in[2];
    const float* Wv = (const float*)d_in[3];
    const float* Wo = (const float*)d_in[4];
    float* out = (float*)d_out;

    const size_t NR = (size_t)B_ * T_;               // 4096
    bf16* ws = (bf16*)d_ws;
    bf16* xb    = ws;                                 // 4096*2048
    bf16* Wqkvt = xb + NR * D_;                       // 3072*2048
    bf16* Wot   = Wqkvt + (size_t)QKVSTR * D_;        // 2048*2048
    bf16* QKVb  = Wot + (size_t)D_ * D_;              // 4096*3072
    bf16* Vtg   = QKVb + NR * QKVSTR;                 // 2*4*128*2048
    bf16* Ab    = Vtg + (size_t)B_ * KV_ * HD_ * T_;  // 4096*2048

    const float qscale = 1.4426950408889634f / sqrtf((float)HD_);

    prep<<<6656, 256, 0, stream>>>(x, Wq, Wk, Wv, Wo, xb, Wqkvt, Wot, qscale);

    // fused QKV projection (256x192 tiles, 256 blocks = exact CU coverage);
    // V columns also written transposed into Vtg
    gemm8<8, 3, bf16, 0, 1><<<dim3(QKVSTR / 192, NR / 256), 512, 0, stream>>>(
        xb, Wqkvt, QKVb, Vtg, (int)NR, QKVSTR, D_);

    flash11<<<dim3(H_, 32), 256, 0, stream>>>(QKVb, QKVb + 2048, Vtg, Ab);

    // output projection (128x256 tiles, 256 blocks)
    gemm8<4, 4, float, 1, 0><<<dim3(D_ / 256, NR / 128), 512, 0, stream>>>(
        Ab, Wot, out, nullptr, (int)NR, D_, H_ * HD_);
}